// Round 3
// baseline (664.943 us; speedup 1.0000x reference)
//
#include <hip/hip_runtime.h>
#include <hip/hip_bf16.h>
#include <stdint.h>

#define N_FEAT 136
#define COL_DOCLEN 14
#define COL_WHOLE_LEN 16
#define COL_TF 24
#define COL_INLINK 127
#define COL_OUTLINK 128
#define COL_PAGERANK 129

// ---------------- Threefry-2x32 (JAX-compatible, 20 rounds) ----------------
__device__ __forceinline__ void threefry2x32(uint32_t k0, uint32_t k1,
                                             uint32_t& x0, uint32_t& x1) {
  const uint32_t ks0 = k0, ks1 = k1, ks2 = k0 ^ k1 ^ 0x1BD11BDAu;
  x0 += ks0; x1 += ks1;
#define TF_ROUND(r) { x0 += x1; x1 = (x1 << (r)) | (x1 >> (32 - (r))); x1 ^= x0; }
  TF_ROUND(13) TF_ROUND(15) TF_ROUND(26) TF_ROUND(6)
  x0 += ks1; x1 += ks2 + 1u;
  TF_ROUND(17) TF_ROUND(29) TF_ROUND(16) TF_ROUND(24)
  x0 += ks2; x1 += ks0 + 2u;
  TF_ROUND(13) TF_ROUND(15) TF_ROUND(26) TF_ROUND(6)
  x0 += ks0; x1 += ks1 + 3u;
  TF_ROUND(17) TF_ROUND(29) TF_ROUND(16) TF_ROUND(24)
  x0 += ks1; x1 += ks2 + 4u;
  TF_ROUND(13) TF_ROUND(15) TF_ROUND(26) TF_ROUND(6)
  x0 += ks2; x1 += ks0 + 5u;
#undef TF_ROUND
}

// ---------------- Kernel 1: sum of column 16 over all docs ----------------
__global__ void col16_sum_kernel(const float* __restrict__ gf, float* __restrict__ sum,
                                 int n_docs) {
  int stride = gridDim.x * blockDim.x;
  float v = 0.f;
  for (int j = blockIdx.x * blockDim.x + threadIdx.x; j < n_docs; j += stride)
    v += gf[(size_t)j * N_FEAT + COL_WHOLE_LEN];
  // wave-64 reduce
  for (int off = 32; off > 0; off >>= 1) v += __shfl_down(v, off, 64);
  __shared__ float ws[4];
  int lane = threadIdx.x & 63, wave = threadIdx.x >> 6;
  if (lane == 0) ws[wave] = v;
  __syncthreads();
  if (threadIdx.x == 0) {
    float t = 0.f;
    int nw = blockDim.x >> 6;
    for (int w = 0; w < nw; ++w) t += ws[w];
    atomicAdd(sum, t);
  }
}

// ---------------- Kernel 2: gather + score ----------------
__global__ void score_kernel(const int* __restrict__ idx,
                             const float* __restrict__ gf,
                             const float* __restrict__ p_k1,
                             const float* __restrict__ p_b,
                             const float* __restrict__ p_bm25w,
                             const float* __restrict__ p_prw,
                             const float* __restrict__ p_inw,
                             const float* __restrict__ p_outw,
                             const float* __restrict__ p_fresh,
                             const float* __restrict__ col_sum,
                             float* __restrict__ out,
                             int batch, float total_docs) {
  int i = blockIdx.x * blockDim.x + threadIdx.x;
  if (i >= batch) return;

  const float k1 = p_k1[0];
  const float b  = p_b[0];
  const float bm25w = p_bm25w[0];
  const float prw   = p_prw[0];
  const float inw   = p_inw[0];
  const float outw  = p_outw[0];
  const float fresh = p_fresh[0];
  const float avg_doc_len = col_sum[0] / total_docs;

  // idf: num_docs_with_term == total_docs
  const float idf = logf(0.5f / (total_docs + 0.5f) + 1.0f);

  const size_t base = (size_t)idx[i] * N_FEAT;
  const float tf   = gf[base + COL_TF];
  const float dl   = gf[base + COL_DOCLEN];
  const float pr   = gf[base + COL_PAGERANK];
  const float inl  = gf[base + COL_INLINK];
  const float outl = gf[base + COL_OUTLINK];

  const float numer = tf * (k1 + 1.0f);
  const float denom = tf + k1 * (1.0f - b + b * (dl / avg_doc_len));
  const float bm25 = idf * (numer / denom);

  // JAX partitionable threefry: counter = 64-bit iota split (hi=0, lo=i),
  // key = (0,1); for 32-bit output, bits = out0 ^ out1.
  uint32_t x0 = 0u, x1 = (uint32_t)i;
  threefry2x32(0u, 1u, x0, x1);
  const uint32_t bits = x0 ^ x1;
  const float noise = __uint_as_float((bits >> 9) | 0x3f800000u) - 1.0f;

  out[i] = bm25w * bm25 + prw * pr + inw * inl + outw * outl + noise * fresh;
}

extern "C" void kernel_launch(void* const* d_in, const int* in_sizes, int n_in,
                              void* d_out, int out_size, void* d_ws, size_t ws_size,
                              hipStream_t stream) {
  const int*   batch_indices = (const int*)d_in[0];
  const float* gf            = (const float*)d_in[1];
  const float* k1    = (const float*)d_in[2];
  const float* b     = (const float*)d_in[3];
  const float* bm25w = (const float*)d_in[4];
  const float* prw   = (const float*)d_in[5];
  const float* inw   = (const float*)d_in[6];
  const float* outw  = (const float*)d_in[7];
  const float* fresh = (const float*)d_in[8];
  float* out = (float*)d_out;
  float* col_sum = (float*)d_ws;

  const int batch  = in_sizes[0];
  const int n_docs = in_sizes[1] / N_FEAT;

  hipMemsetAsync(col_sum, 0, sizeof(float), stream);

  col16_sum_kernel<<<1024, 256, 0, stream>>>(gf, col_sum, n_docs);

  const int threads = 256;
  const int blocks = (batch + threads - 1) / threads;
  score_kernel<<<blocks, threads, 0, stream>>>(
      batch_indices, gf, k1, b, bm25w, prw, inw, outw, fresh,
      col_sum, out, batch, (float)n_docs);
}